// Round 7
// baseline (119.069 us; speedup 1.0000x reference)
//
#include <hip/hip_runtime.h>
#include <hip/hip_cooperative_groups.h>

namespace cg = cooperative_groups;

#define N_NODES 10000
#define N_EDGES 320000
#define F 256          // F_IN == F_OUT
#define K2 512         // 2*F_IN
#define GRID_B 512
#define BLK 256
#define N_TILE16 625
#define N_TILE64 157   // ceil(10000/64)
#define AT_TILES 628   // padded to N_TILE64*4 so 64-row GEMM may read (not store) past end
#define SCAN_T 1024
#define SCAN_CH 10

#define FEAT_BLOCKS (N_NODES * F / 4 / 256)   // 2500
#define W_BLOCKS (F * K2 / 4 / 256)           // 128

typedef __attribute__((ext_vector_type(8))) __bf16 bf16x8;
typedef __attribute__((ext_vector_type(4))) __bf16 bf16x4;
typedef __attribute__((ext_vector_type(4))) float f32x4;
typedef unsigned long long u64;
typedef unsigned int u32;
typedef unsigned short u16;

__device__ inline float bf2f(u16 u) { u32 x = ((u32)u) << 16; return __uint_as_float(x); }

// Tiled A layout: AT[tile16][t][kq][n16][8e]; tile16=node/16, t=k/32, kq=(k%32)/8, e=k%8.
// Tiled W layout: Wt[t][kq][col][8e].

// ===================== shared device helpers (used by both paths) =====================

__device__ inline void do_feat_item(int it, const float* feat, __bf16* featb, __bf16* AT) {
  int node = it >> 6;                     // 64 float4 per row
  int k = (it & 63) * 4;
  float4 v = ((const float4*)feat)[it];
  bf16x4 o;
  o[0] = (__bf16)v.x; o[1] = (__bf16)v.y; o[2] = (__bf16)v.z; o[3] = (__bf16)v.w;
  *(bf16x4*)(featb + (size_t)it * 4) = o; // plain row-major for gather
  int tile = node >> 4, n16 = node & 15;
  int t = k >> 5, kq = (k & 31) >> 3, e = k & 7;
  size_t offT = ((((size_t)tile * 16 + t) * 4 + kq) * 16 + n16) * 8 + e;
  *(bf16x4*)(AT + offT) = o;              // fragment-tiled feat half
}

__device__ inline void do_w_item(int idx, const float* Wm, const float* feat,
                                 const int* src, __bf16* Wt) {
  int o_ = idx >> 7;                      // 128 float4 per W row
  int k = (idx & 127) * 4;
  float4 w = ((const float4*)Wm)[idx];
  if (k >= F) {
    int s0 = src[0];
    float4 h = ((const float4*)(feat + (size_t)s0 * F))[(k - F) >> 2];
    w.x *= h.x; w.y *= h.y; w.z *= h.z; w.w *= h.w;
  }
  bf16x4 o;
  o[0] = (__bf16)w.x; o[1] = (__bf16)w.y; o[2] = (__bf16)w.z; o[3] = (__bf16)w.w;
  int t = k >> 5, kq = (k & 31) >> 3, e = k & 7;
  size_t offT = (((size_t)t * 4 + kq) * 256 + o_) * 8 + e;
  *(bf16x4*)(Wt + offT) = o;
}

__device__ inline void do_agg_node(int node, int lane, const __bf16* featb,
                                   const int* off, const u64* epack, __bf16* AT) {
  int beg = off[node], end = off[node + 1];
  float ax = 0.f, ay = 0.f, az = 0.f, aw = 0.f;
  const ushort4* f4 = (const ushort4*)featb;
  int i = beg;
  for (; i + 4 <= end; i += 4) {
    u64 p0 = epack[i], p1 = epack[i + 1], p2 = epack[i + 2], p3 = epack[i + 3];
    ushort4 v0 = f4[(size_t)(u32)p0 * 64 + lane];
    ushort4 v1 = f4[(size_t)(u32)p1 * 64 + lane];
    ushort4 v2 = f4[(size_t)(u32)p2 * 64 + lane];
    ushort4 v3 = f4[(size_t)(u32)p3 * 64 + lane];
    float w0 = __uint_as_float((u32)(p0 >> 32));
    float w1 = __uint_as_float((u32)(p1 >> 32));
    float w2 = __uint_as_float((u32)(p2 >> 32));
    float w3 = __uint_as_float((u32)(p3 >> 32));
    ax += bf2f(v0.x) * w0 + bf2f(v1.x) * w1 + bf2f(v2.x) * w2 + bf2f(v3.x) * w3;
    ay += bf2f(v0.y) * w0 + bf2f(v1.y) * w1 + bf2f(v2.y) * w2 + bf2f(v3.y) * w3;
    az += bf2f(v0.z) * w0 + bf2f(v1.z) * w1 + bf2f(v2.z) * w2 + bf2f(v3.z) * w3;
    aw += bf2f(v0.w) * w0 + bf2f(v1.w) * w1 + bf2f(v2.w) * w2 + bf2f(v3.w) * w3;
  }
  for (; i < end; ++i) {
    u64 p0 = epack[i];
    ushort4 v0 = f4[(size_t)(u32)p0 * 64 + lane];
    float w0 = __uint_as_float((u32)(p0 >> 32));
    ax += bf2f(v0.x) * w0; ay += bf2f(v0.y) * w0;
    az += bf2f(v0.z) * w0; aw += bf2f(v0.w) * w0;
  }
  float ic = 1.0f / (float)max(end - beg, 1);
  bf16x4 o;
  o[0] = (__bf16)(ax * ic); o[1] = (__bf16)(ay * ic);
  o[2] = (__bf16)(az * ic); o[3] = (__bf16)(aw * ic);
  int tile = node >> 4, n16 = node & 15;
  int t = 8 + (lane >> 3);
  int kq = (lane & 7) >> 1;
  int e = (lane & 1) * 4;
  size_t offT = ((((size_t)tile * 16 + t) * 4 + kq) * 16 + n16) * 8 + e;
  *(bf16x4*)(AT + offT) = o;
}

// 64-row x 256-col GEMM macro-tile; wave = 64 rows x 64 cols, B reused across 4 row-subtiles
__device__ inline void do_gemm64_tile(int tile64, int tid, const __bf16* AT,
                                      const __bf16* Wt, const float* bias,
                                      float* out) {
  const int lane = tid & 63;
  const int wave = tid >> 6;
  const int r15 = lane & 15;
  const int kq = lane >> 4;
  const int col0 = wave * 64;
  f32x4 acc[4][4];
#pragma unroll
  for (int rs = 0; rs < 4; ++rs)
#pragma unroll
    for (int cs = 0; cs < 4; ++cs) acc[rs][cs] = (f32x4){0.f, 0.f, 0.f, 0.f};

#pragma unroll
  for (int t = 0; t < 16; ++t) {
    bf16x8 a[4];
#pragma unroll
    for (int rs = 0; rs < 4; ++rs) {
      size_t tile16 = (size_t)tile64 * 4 + rs;
      a[rs] = *(const bf16x8*)(AT + (((tile16 * 16 + t) * 4 + kq) * 16 + r15) * 8);
    }
#pragma unroll
    for (int cs = 0; cs < 4; ++cs) {
      bf16x8 bb = *(const bf16x8*)(Wt + (((size_t)t * 4 + kq) * 256 + col0 + cs * 16 + r15) * 8);
#pragma unroll
      for (int rs = 0; rs < 4; ++rs)
        acc[rs][cs] = __builtin_amdgcn_mfma_f32_16x16x32_bf16(a[rs], bb, acc[rs][cs], 0, 0, 0);
    }
  }

  // C/D layout: col = lane&15, row = (lane>>4)*4 + reg   [m89-verified]
  int m0 = tile64 * 64;
  int rbase = kq * 4;
#pragma unroll
  for (int cs = 0; cs < 4; ++cs) {
    int col = col0 + cs * 16 + r15;
    float bv = bias[col];
#pragma unroll
    for (int rs = 0; rs < 4; ++rs) {
#pragma unroll
      for (int r = 0; r < 4; ++r) {
        int orow = m0 + rs * 16 + rbase + r;
        if (orow < N_NODES)
          out[(size_t)orow * F + col] = fmaxf(acc[rs][cs][r] + bv, 0.0f);
      }
    }
  }
}

// ===================== cooperative mega-kernel =====================

__global__ __launch_bounds__(BLK, 2) void mega_kernel(
    const float* __restrict__ feat,
    const float* __restrict__ ew,
    const int* __restrict__ src,
    const int* __restrict__ dst,
    const float* __restrict__ Wm,
    const float* __restrict__ bias,
    float* __restrict__ out,
    u64* __restrict__ epack,
    __bf16* __restrict__ featb,
    __bf16* __restrict__ AT,
    __bf16* __restrict__ Wt,
    int* __restrict__ off,
    int* __restrict__ cursor,
    int* __restrict__ deg) {
  cg::grid_group grid = cg::this_grid();
  __shared__ int part[BLK];

  const int tid = threadIdx.x;
  const int bid = blockIdx.x;
  const int gtid = bid * BLK + tid;
  const int nthr = GRID_B * BLK;

  // P0: deg = 0
  for (int i = gtid; i < N_NODES; i += nthr) deg[i] = 0;
  grid.sync();

  // P1: histogram of dst
  for (int i = gtid; i < N_EDGES / 4; i += nthr) {
    int4 d = ((const int4*)dst)[i];
    atomicAdd(&deg[d.x], 1);
    atomicAdd(&deg[d.y], 1);
    atomicAdd(&deg[d.z], 1);
    atomicAdd(&deg[d.w], 1);
  }
  grid.sync();

  // P2: block 0 scans; other blocks do bf16 conversion + fragment tiling
  if (bid == 0) {
    int base = tid * 40;
    int s = 0;
    for (int j = 0; j < 40; ++j) {
      int i = base + j;
      if (i < N_NODES) s += deg[i];
    }
    part[tid] = s;
    __syncthreads();
    for (int ofs = 1; ofs < BLK; ofs <<= 1) {
      int v = (tid >= ofs) ? part[tid - ofs] : 0;
      __syncthreads();
      part[tid] += v;
      __syncthreads();
    }
    int run = part[tid] - s;
    for (int j = 0; j < 40; ++j) {
      int i = base + j;
      if (i < N_NODES) {
        off[i] = run;
        cursor[i] = run;
        run += deg[i];
      }
    }
    if (tid == BLK - 1) off[N_NODES] = part[BLK - 1];
  } else {
    int base2 = (bid - 1) * BLK + tid;
    int nthr2 = (GRID_B - 1) * BLK;
    const int FEAT_ITEMS = N_NODES * F / 4;
    const int W_ITEMS = F * K2 / 4;
    for (int it = base2; it < FEAT_ITEMS + W_ITEMS; it += nthr2) {
      if (it < FEAT_ITEMS) do_feat_item(it, feat, featb, AT);
      else do_w_item(it - FEAT_ITEMS, Wm, feat, src, Wt);
    }
  }
  grid.sync();

  // P3: scatter packed (ew,src)
  for (int i = gtid; i < N_EDGES / 4; i += nthr) {
    int4 s4 = ((const int4*)src)[i];
    int4 d4 = ((const int4*)dst)[i];
    float4 w4 = ((const float4*)ew)[i];
    int p;
    p = atomicAdd(&cursor[d4.x], 1);
    epack[p] = ((u64)__float_as_uint(w4.x) << 32) | (u32)s4.x;
    p = atomicAdd(&cursor[d4.y], 1);
    epack[p] = ((u64)__float_as_uint(w4.y) << 32) | (u32)s4.y;
    p = atomicAdd(&cursor[d4.z], 1);
    epack[p] = ((u64)__float_as_uint(w4.z) << 32) | (u32)s4.z;
    p = atomicAdd(&cursor[d4.w], 1);
    epack[p] = ((u64)__float_as_uint(w4.w) << 32) | (u32)s4.w;
  }
  grid.sync();

  // P4: aggregation, one wave per node
  {
    const int lane = tid & 63;
    const int wid = gtid >> 6;
    const int nwaves = nthr >> 6;
    for (int node = wid; node < N_NODES; node += nwaves)
      do_agg_node(node, lane, featb, off, epack, AT);
  }
  grid.sync();

  // P5: MFMA GEMM, 64-row macro-tiles
  for (int tile64 = bid; tile64 < N_TILE64; tile64 += GRID_B)
    do_gemm64_tile(tile64, tid, AT, Wt, bias, out);
}

// ===================== fallback discrete kernels =====================

__global__ __launch_bounds__(256) void prep_all_kernel(
    const float* __restrict__ feat,
    const float* __restrict__ Wm,
    const int* __restrict__ src,
    __bf16* __restrict__ featb,
    __bf16* __restrict__ AT,
    __bf16* __restrict__ Wt,
    int* __restrict__ deg) {
  int b = blockIdx.x;
  int tid = threadIdx.x;
  if (b < FEAT_BLOCKS) {
    int idx = b * 256 + tid;
    do_feat_item(idx, feat, featb, AT);
    if (idx < N_NODES) deg[idx] = 0;
  } else {
    do_w_item((b - FEAT_BLOCKS) * 256 + tid, Wm, feat, src, Wt);
  }
}

__global__ __launch_bounds__(256) void hist_kernel(const int* __restrict__ dst,
                                                   int* __restrict__ deg) {
  int i = blockIdx.x * 256 + threadIdx.x;
  if (i >= N_EDGES / 4) return;
  int4 d = ((const int4*)dst)[i];
  atomicAdd(&deg[d.x], 1);
  atomicAdd(&deg[d.y], 1);
  atomicAdd(&deg[d.z], 1);
  atomicAdd(&deg[d.w], 1);
}

__global__ __launch_bounds__(SCAN_T) void scan_kernel(const int* __restrict__ deg,
                                                      int* __restrict__ off,
                                                      int* __restrict__ cursor) {
  __shared__ int part[SCAN_T];
  int t = threadIdx.x;
  int base = t * SCAN_CH;
  int local[SCAN_CH];
  int s = 0;
  for (int j = 0; j < SCAN_CH; ++j) {
    int i = base + j;
    int d = (i < N_NODES) ? deg[i] : 0;
    local[j] = s;
    s += d;
  }
  part[t] = s;
  __syncthreads();
  for (int ofs = 1; ofs < SCAN_T; ofs <<= 1) {
    int v = (t >= ofs) ? part[t - ofs] : 0;
    __syncthreads();
    part[t] += v;
    __syncthreads();
  }
  int excl = part[t] - s;
  for (int j = 0; j < SCAN_CH; ++j) {
    int i = base + j;
    if (i < N_NODES) {
      int o = excl + local[j];
      off[i] = o;
      cursor[i] = o;
    }
  }
  if (t == SCAN_T - 1) off[N_NODES] = part[SCAN_T - 1];
}

__global__ __launch_bounds__(256) void scatter_kernel(const int* __restrict__ src,
                                                      const int* __restrict__ dst,
                                                      const float* __restrict__ ew,
                                                      int* __restrict__ cursor,
                                                      u64* __restrict__ epack) {
  int i = blockIdx.x * 256 + threadIdx.x;
  if (i >= N_EDGES / 4) return;
  int4 s4 = ((const int4*)src)[i];
  int4 d4 = ((const int4*)dst)[i];
  float4 w4 = ((const float4*)ew)[i];
  int p;
  p = atomicAdd(&cursor[d4.x], 1);
  epack[p] = ((u64)__float_as_uint(w4.x) << 32) | (u32)s4.x;
  p = atomicAdd(&cursor[d4.y], 1);
  epack[p] = ((u64)__float_as_uint(w4.y) << 32) | (u32)s4.y;
  p = atomicAdd(&cursor[d4.z], 1);
  epack[p] = ((u64)__float_as_uint(w4.z) << 32) | (u32)s4.z;
  p = atomicAdd(&cursor[d4.w], 1);
  epack[p] = ((u64)__float_as_uint(w4.w) << 32) | (u32)s4.w;
}

__global__ __launch_bounds__(256) void node_agg_kernel(
    const __bf16* __restrict__ featb,
    const int* __restrict__ off,
    const u64* __restrict__ epack,
    __bf16* __restrict__ AT) {
  int node = (blockIdx.x * 256 + threadIdx.x) >> 6;
  int lane = threadIdx.x & 63;
  if (node >= N_NODES) return;
  do_agg_node(node, lane, featb, off, epack, AT);
}

__global__ __launch_bounds__(256) void mfma_gemm_kernel(
    const __bf16* __restrict__ AT,
    const __bf16* __restrict__ Wt,
    const float* __restrict__ bias,
    float* __restrict__ out) {
  do_gemm64_tile(blockIdx.x, threadIdx.x, AT, Wt, bias, out);
}

// ===================== launcher =====================

extern "C" void kernel_launch(void* const* d_in, const int* in_sizes, int n_in,
                              void* d_out, int out_size, void* d_ws, size_t ws_size,
                              hipStream_t stream) {
  const float* feat = (const float*)d_in[0];
  const float* ew   = (const float*)d_in[1];
  const int*   src  = (const int*)d_in[2];
  const int*   dst  = (const int*)d_in[3];
  const float* Wm   = (const float*)d_in[4];
  const float* bias = (const float*)d_in[5];
  float* out = (float*)d_out;

  // workspace layout (8B-aligned first)
  u64*    epack = (u64*)d_ws;                                  // E
  __bf16* featb = (__bf16*)(epack + N_EDGES);                  // N*F plain
  __bf16* AT    = featb + (size_t)N_NODES * F;                 // AT_TILES*16KB (padded)
  __bf16* Wt    = AT + (size_t)AT_TILES * 8192;                // F*K2 tiled
  int*    off   = (int*)(Wt + (size_t)F * K2);                 // N+1
  int*    cursor= off + N_NODES + 1;                           // N
  int*    deg   = cursor + N_NODES;                            // N

  void* args[] = {
    (void*)&feat, (void*)&ew, (void*)&src, (void*)&dst, (void*)&Wm,
    (void*)&bias, (void*)&out, (void*)&epack, (void*)&featb, (void*)&AT,
    (void*)&Wt, (void*)&off, (void*)&cursor, (void*)&deg
  };

  // Gate cooperative path: device support + enough co-resident blocks; verify launch rc.
  hipError_t lerr = hipErrorUnknown;
  int dev = 0;
  (void)hipGetDevice(&dev);
  int coopOK = 0;
  (void)hipDeviceGetAttribute(&coopOK, hipDeviceAttributeCooperativeLaunch, dev);
  if (coopOK) {
    int maxBlk = 0;
    hipError_t qerr = hipOccupancyMaxActiveBlocksPerMultiprocessor(
        &maxBlk, (const void*)mega_kernel, BLK, 0);
    if (qerr == hipSuccess && maxBlk * 256 >= GRID_B) {   // 256 CUs on MI355X
      lerr = hipLaunchCooperativeKernel((void*)mega_kernel, dim3(GRID_B), dim3(BLK),
                                        args, 0, stream);
    }
  }
  if (lerr != hipSuccess) {
    // fallback: discrete pipeline (known-good R5 structure + 64-row GEMM)
    prep_all_kernel<<<FEAT_BLOCKS + W_BLOCKS, 256, 0, stream>>>(feat, Wm, src, featb, AT, Wt, deg);
    hist_kernel<<<(N_EDGES / 4 + 255) / 256, 256, 0, stream>>>(dst, deg);
    scan_kernel<<<1, SCAN_T, 0, stream>>>(deg, off, cursor);
    scatter_kernel<<<(N_EDGES / 4 + 255) / 256, 256, 0, stream>>>(src, dst, ew, cursor, epack);
    node_agg_kernel<<<(N_NODES * 64 + 255) / 256, 256, 0, stream>>>(featb, off, epack, AT);
    mfma_gemm_kernel<<<N_TILE64, 256, 0, stream>>>(AT, Wt, bias, out);
  }
}